// Round 3
// baseline (1928.930 us; speedup 1.0000x reference)
//
#include <hip/hip_runtime.h>
#include <hip/hip_bf16.h>
#include <math.h>

#define EMBC   192
#define HIDC   64
#define NLAY   6
#define IMGC   224
#define FMAPC  56
#define NNODE  3136      // 56*56
#define NBATCH 8
#define BNODES 25088     // NBATCH*NNODE
#define KNNE   8
#define RSQRT2 0.70710678118654752f

__device__ __forceinline__ float sigm(float x){ return 1.0f/(1.0f+__expf(-x)); }

// ---------------- K0: transpose stem_g / (stem_b+pos) to [n][c] ----------------
__global__ void k_tr(const float* __restrict__ g, const float* __restrict__ sb,
                     const float* __restrict__ pe, float* __restrict__ g2,
                     float* __restrict__ pb2){
  int n = blockIdx.x; int c = threadIdx.x;
  g2[n*EMBC + c]  = g[c*NNODE + n];
  pb2[n*EMBC + c] = sb[c*NNODE + n] + pe[c*NNODE + n];
}

// ---------------- K1: stem conv (4x4 stride 4) + LN partial sums ----------------
__global__ __launch_bounds__(256) void k_conv(const float* __restrict__ x,
    const float* __restrict__ cw, const float* __restrict__ cb,
    float* __restrict__ y0, float* __restrict__ parts){
  __shared__ float xs[2688];
  __shared__ float wsh[9216];
  __shared__ float red[512];
  int blk = blockIdx.x; int b = blk / FMAPC; int ph = blk % FMAPC;
  int tid = threadIdx.x;
  for(int t = tid; t < 9216; t += 256) wsh[t] = cw[t];
  for(int t = tid; t < 2688; t += 256){
    int r = t / IMGC; int w = t % IMGC;
    int ci = r >> 2, kh = r & 3;
    xs[t] = x[((size_t)(b*3 + ci)*IMGC + (ph*4 + kh))*IMGC + w];
  }
  __syncthreads();
  float s1 = 0.f, s2 = 0.f;
  for(int oi = tid; oi < FMAPC*EMBC; oi += 256){
    int pw = oi / EMBC; int c = oi % EMBC;
    float acc = cb[c];
    const float4* wv4 = (const float4*)(wsh + c*48);
    #pragma unroll
    for(int r = 0; r < 12; ++r){
      float4 xv = *((const float4*)(xs + r*IMGC + pw*4));
      float4 wv = wv4[r];
      acc += xv.x*wv.x + xv.y*wv.y + xv.z*wv.z + xv.w*wv.w;
    }
    y0[((size_t)(b*NNODE + ph*FMAPC + pw))*EMBC + c] = acc;
    s1 += acc; s2 += acc*acc;
  }
  red[tid] = s1; red[256+tid] = s2;
  __syncthreads();
  for(int st = 128; st > 0; st >>= 1){
    if(tid < st){ red[tid] += red[tid+st]; red[256+tid] += red[256+tid+st]; }
    __syncthreads();
  }
  if(tid == 0){ parts[blk*2] = red[0]; parts[blk*2+1] = red[256]; }
}

// ---------------- K2: finalize per-batch LN stats ----------------
__global__ void k_stats(const float* __restrict__ parts, float* __restrict__ stats){
  int b = threadIdx.x;
  if(b < NBATCH){
    float S = 0.f, Q = 0.f;
    for(int j = 0; j < FMAPC; ++j){ S += parts[(b*FMAPC+j)*2]; Q += parts[(b*FMAPC+j)*2+1]; }
    float cnt = (float)(EMBC*NNODE);
    float mu = S/cnt;
    float var = Q/cnt - mu*mu;
    stats[b*2] = mu; stats[b*2+1] = rsqrtf(var + 1e-5f);
  }
}

// ---------------- K3: LN + pos + embed + mvlin_flat(in_W) -> x_mv ----------------
__global__ __launch_bounds__(256) void k_embed(const float* __restrict__ y0,
    const float* __restrict__ stats, const float* __restrict__ g2,
    const float* __restrict__ pb2, const float* __restrict__ inW,
    const float* __restrict__ inb, const float* __restrict__ coords,
    float* __restrict__ xmv){
  __shared__ float Ws[64*193];
  __shared__ float fs[192];
  __shared__ float red[256];
  int tid = threadIdx.x;
  for(int t = tid; t < 64*193; t += 256) Ws[t] = inW[t];
  int ch = tid & 63, q = tid >> 6;
  int pend = blockIdx.x*16 + 16;
  for(int p = blockIdx.x*16; p < pend; ++p){
    int b = p / NNODE, n = p % NNODE;
    float mu = stats[b*2], rstd = stats[b*2+1];
    __syncthreads();
    if(tid < EMBC)
      fs[tid] = (y0[(size_t)p*EMBC + tid] - mu)*rstd*g2[n*EMBC+tid] + pb2[n*EMBC+tid];
    __syncthreads();
    float part = 0.f;
    const float* wr = Ws + ch*193 + q*48;
    const float* fr = fs + q*48;
    #pragma unroll 8
    for(int c = 0; c < 48; ++c) part += wr[c]*fr[c];
    red[tid] = part;
    __syncthreads();
    if(q == 0){
      float x0 = inb[ch] + red[ch] + red[64+ch] + red[128+ch] + red[192+ch];
      float wc = Ws[ch*193 + 192];
      float cx = coords[n*2], cy = coords[n*2+1];
      float4 v; v.x = x0; v.y = wc*cx; v.z = wc*cy; v.w = 0.f;
      *((float4*)(xmv + ((size_t)p*64 + ch)*4)) = v;
    }
  }
}

// ---------------- K5: z = mvlin(h, W) (no bias), weights pinned in VGPRs ----------------
__global__ __launch_bounds__(256,1) void k_mvlin(const float* __restrict__ src,
    float* __restrict__ dst, const float* __restrict__ W, int npb){
  __shared__ float xs[256];
  int tid = threadIdx.x;
  int ch = tid & 63, bi = tid >> 6;
  int g = (bi==0)?0:((bi==3)?2:1);
  float w[64];
  #pragma unroll
  for(int m = 0; m < 64; ++m) w[m] = W[(ch*64+m)*3 + g];
  #pragma unroll
  for(int m = 0; m < 64; ++m) asm volatile("" : "+v"(w[m]));
  int p0 = blockIdx.x * npb;
  for(int p = p0; p < p0 + npb; ++p){
    __syncthreads();
    xs[(tid&3)*64 + (tid>>2)] = src[(size_t)p*256 + tid];
    __syncthreads();
    float acc = 0.f;
    const float4* xv = (const float4*)(xs + bi*64);
    #pragma unroll
    for(int m4 = 0; m4 < 16; ++m4){
      float4 v = xv[m4];
      acc += w[m4*4]*v.x + w[m4*4+1]*v.y + w[m4*4+2]*v.z + w[m4*4+3]*v.w;
    }
    dst[(p*64 + ch)*4 + bi] = acc;
  }
}

// ---------------- K7: fused edge-agg + nu matmul ----------------
__global__ __launch_bounds__(512,1) void k_nu(const float* __restrict__ h,
    const float* __restrict__ z, const int* __restrict__ cols,
    const float* __restrict__ eb, const float* __restrict__ sa,
    const float* __restrict__ sb, float* __restrict__ nu,
    const float* __restrict__ W, const float* __restrict__ nb, int npb){
  __shared__ float aggs[8*256];   // [j][bi*64+m]
  __shared__ float xs[256];       // h of current node, [bi*64+m]
  __shared__ float ps[512];
  int tid = threadIdx.x;
  int ch = tid & 63, bi = (tid >> 6) & 3, half = tid >> 8;
  int j = tid >> 6;               // wave id 0..7 (phase A)
  int g = (bi==0)?0:((bi==3)?2:1);
  float w[64];
  #pragma unroll
  for(int m = 0; m < 64; ++m) w[m] = W[(ch*128 + half*64 + m)*3 + g];
  #pragma unroll
  for(int m = 0; m < 64; ++m) asm volatile("" : "+v"(w[m]));
  float bias = nb[ch];
  float ebv = eb[ch];
  float a0 = sa[ch*3], a1 = sa[ch*3+1], a2 = sa[ch*3+2];
  float b0 = sb[ch*3], b1 = sb[ch*3+1], b2 = sb[ch*3+2];
  int p0blk = blockIdx.x * npb;
  for(int g8 = 0; g8 < npb/8; ++g8){
    int p0 = p0blk + g8*8;
    __syncthreads();   // protect aggs/xs from previous group's readers
    { // phase A: wave j aggregates node p0+j
      int p = p0 + j;
      float4 zo = *((const float4*)(z + ((size_t)p*64 + ch)*4));
      float ax=0.f, ay=0.f, az=0.f, aw=0.f;
      #pragma unroll
      for(int k = 0; k < KNNE; ++k){
        int c = cols[p*KNNE + k];
        float4 zc = *((const float4*)(z + ((size_t)c*64 + ch)*4));
        float d0 = zo.x - zc.x + ebv;
        float d1 = zo.y - zc.y;
        float d2 = zo.z - zc.z;
        float d3 = zo.w - zc.w;
        float g0 = sigm(a0*d0 + b0);
        float g1 = sigm(a1*(d1*d1 + d2*d2) + b1);
        float g2v = sigm(a2*(d3*d3) + b2);
        ax += g0*d0; ay += g1*d1; az += g1*d2; aw += g2v*d3;
      }
      aggs[j*256 +       ch] = ax;
      aggs[j*256 +  64 + ch] = ay;
      aggs[j*256 + 128 + ch] = az;
      aggs[j*256 + 192 + ch] = aw;
    }
    for(int jj = 0; jj < 8; ++jj){
      int p = p0 + jj;
      __syncthreads();
      if(tid < 256) xs[(tid&3)*64 + (tid>>2)] = h[(size_t)p*256 + tid];
      __syncthreads();
      float acc = 0.f;
      const float4* xv = (const float4*)((half==0) ? (xs + bi*64) : (aggs + jj*256 + bi*64));
      #pragma unroll
      for(int m4 = 0; m4 < 16; ++m4){
        float4 v = xv[m4];
        acc += w[m4*4]*v.x + w[m4*4+1]*v.y + w[m4*4+2]*v.z + w[m4*4+3]*v.w;
      }
      ps[tid] = acc;
      __syncthreads();
      if(tid < 256){
        float a = ps[tid] + ps[tid + 256] + ((bi==0)? bias : 0.f);
        nu[(p*64 + ch)*4 + bi] = a;
      }
    }
  }
}

// ---------------- K8: sgp (+ optional mv_silu, + optional residual) -- 512 thr ----------------
__global__ __launch_bounds__(512,1) void k_sgp(const float* __restrict__ src,
    float* __restrict__ h, const float* __restrict__ Wl, const float* __restrict__ bl,
    const float* __restrict__ Wr, const float* __restrict__ na,
    const float* __restrict__ gw, const float* __restrict__ aa,
    const float* __restrict__ ab, int mode, int npb){
  __shared__ float xs[256];
  __shared__ float yrs[320];
  __shared__ float xrs[320];
  __shared__ float ous[320];
  int tid = threadIdx.x;
  int ch = tid & 63, bi = (tid >> 6) & 3, half = tid >> 8;
  int g = (bi==0)?0:((bi==3)?2:1);
  const float* Wsel = half ? Wr : Wl;
  float w[64];
  #pragma unroll
  for(int m = 0; m < 64; ++m) w[m] = Wsel[(ch*64+m)*3 + g];
  #pragma unroll
  for(int m = 0; m < 64; ++m) asm volatile("" : "+v"(w[m]));
  float blv = bl[ch];
  float nav = sigm(na[ch*3 + g]);
  float wA, wB, wC, wD = 0.f;
  if(bi==0)      { wA=gw[ch*10+0]; wB=gw[ch*10+3]; wC=gw[ch*10+7]; }
  else if(bi==3) { wA=gw[ch*10+2]; wB=gw[ch*10+6]; wC=gw[ch*10+9]; }
  else           { wA=gw[ch*10+1]; wB=gw[ch*10+4]; wC=gw[ch*10+5]; wD=gw[ch*10+8]; }
  float aav = 0.f, abv = 0.f;
  if(mode != 0){ aav = aa[ch*3+g]; abv = ab[ch*3+g]; }
  int p0 = blockIdx.x * npb;
  for(int p = p0; p < p0 + npb; ++p){
    __syncthreads();
    if(tid < 256) xs[(tid&3)*64 + (tid>>2)] = src[(size_t)p*256 + tid];
    __syncthreads();
    float acc = (half==0 && bi==0)? blv : 0.f;
    const float4* xv = (const float4*)(xs + bi*64);
    #pragma unroll
    for(int m4 = 0; m4 < 16; ++m4){
      float4 v = xv[m4];
      acc += w[m4*4]*v.x + w[m4*4+1]*v.y + w[m4*4+2]*v.z + w[m4*4+3]*v.w;
    }
    if(half == 1) yrs[ch*5 + bi] = acc;
    __syncthreads();
    if(half == 1){
      float q;
      if(g==0)      { q = acc*acc; }
      else if(g==1) { float u = yrs[ch*5+1], v2 = yrs[ch*5+2]; q = u*u + v2*v2; }
      else          { q = acc*acc; }
      float nn = sqrtf(q + 1e-12f);
      float dd = nav*(nn - 1.f) + 1.f;
      xrs[ch*5 + bi] = acc/(dd + 1e-6f);
    }
    __syncthreads();
    int idx = (p*64 + ch)*4 + bi;
    float o = 0.f;
    if(half == 0){
      float x0 = xs[ch], x1 = xs[64+ch], x2 = xs[128+ch], x3 = xs[192+ch];
      float xr0 = xrs[ch*5+0], xr1 = xrs[ch*5+1], xr2 = xrs[ch*5+2], xr3 = xrs[ch*5+3];
      float gp;
      if(bi==0)      gp = wA*x0*xr0 + wB*(x1*xr1 + x2*xr2) + wC*x3*xr3;
      else if(bi==1) gp = wA*x0*xr1 + wB*x1*xr0 - wC*x2*xr3 - wD*x3*xr2;
      else if(bi==2) gp = wA*x0*xr2 + wB*x2*xr0 + wC*x1*xr3 + wD*x3*xr1;
      else           gp = wA*x0*xr3 + wB*(x1*xr2 - x2*xr1) - wC*x3*xr0;
      o = (acc + gp)*RSQRT2;
      if(mode == 0) h[idx] = o;
      else ous[ch*5 + bi] = o;
    }
    if(mode != 0){
      __syncthreads();
      if(half == 0){
        float inv;
        if(g==0)      inv = ous[ch*5+0];
        else if(g==1) { float u = ous[ch*5+1], v2 = ous[ch*5+2]; inv = u*u + v2*v2; }
        else          { float u = ous[ch*5+3]; inv = u*u; }
        float gate = sigm(aav*inv + abv);
        float val = gate*o;
        if(mode == 2) val += h[idx];
        h[idx] = val;
      }
    }
  }
}

// ---------------- K9: head projection (blade 0) + per-node LN -- 192 thr ----------------
__global__ __launch_bounds__(192) void k_head(const float* __restrict__ h,
    const float* __restrict__ oW, const float* __restrict__ ob,
    const float* __restrict__ ong, const float* __restrict__ onb,
    float* __restrict__ s, int npb){
  __shared__ float hx[64];
  __shared__ float r[6];
  int tid = threadIdx.x; int wv = tid >> 6; int ln = tid & 63;
  float w[64];
  #pragma unroll
  for(int m = 0; m < 64; ++m) w[m] = oW[tid*64 + m];
  #pragma unroll
  for(int m = 0; m < 64; ++m) asm volatile("" : "+v"(w[m]));
  float obv = ob[tid], ongv = ong[tid], onbv = onb[tid];
  int p0 = blockIdx.x * npb;
  for(int p = p0; p < p0 + npb; ++p){
    __syncthreads();
    if(tid < 64) hx[tid] = h[((size_t)p*64 + tid)*4];
    __syncthreads();
    float acc = obv;
    const float4* hv = (const float4*)hx;
    #pragma unroll
    for(int m4 = 0; m4 < 16; ++m4){
      float4 v = hv[m4];
      acc += w[m4*4]*v.x + w[m4*4+1]*v.y + w[m4*4+2]*v.z + w[m4*4+3]*v.w;
    }
    float s1 = acc, s2 = acc*acc;
    #pragma unroll
    for(int off = 32; off > 0; off >>= 1){
      s1 += __shfl_down(s1, off);
      s2 += __shfl_down(s2, off);
    }
    if(ln == 0){ r[wv] = s1; r[3+wv] = s2; }
    __syncthreads();
    float S = r[0]+r[1]+r[2], Q = r[3]+r[4]+r[5];
    float mu = S*(1.0f/EMBC);
    float var = Q*(1.0f/EMBC) - mu*mu;
    float rstd = rsqrtf(var + 1e-5f);
    s[(size_t)p*EMBC + tid] = (acc - mu)*rstd*ongv + onbv;
  }
}

// ---------------- K10: pooling (two-stage, deterministic) ----------------
__global__ void k_pool1(const float* __restrict__ s, float* __restrict__ pp){
  int blk = blockIdx.x;
  int b = blk >> 5, chunk = blk & 31;
  int c = threadIdx.x;
  float acc = 0.f;
  int n0 = chunk*98;
  for(int j = 0; j < 98; ++j) acc += s[((size_t)(b*NNODE + n0 + j))*EMBC + c];
  pp[(size_t)blk*EMBC + c] = acc;
}
__global__ void k_pool2(const float* __restrict__ pp, float* __restrict__ pooled){
  int b = blockIdx.x; int c = threadIdx.x;
  float acc = 0.f;
  for(int j = 0; j < 32; ++j) acc += pp[((size_t)(b*32 + j))*EMBC + c];
  pooled[b*EMBC + c] = acc * (1.0f/NNODE);
}

// ---------------- K11: classifier ----------------
__global__ void k_cls(const float* __restrict__ pooled, const float* __restrict__ cW,
                      const float* __restrict__ cb, float* __restrict__ out){
  int tid = threadIdx.x;
  if(tid < NBATCH*10){
    int b = tid/10, k = tid%10;
    float acc = cb[k];
    for(int c = 0; c < EMBC; ++c) acc += pooled[b*EMBC + c]*cW[k*EMBC + c];
    out[tid] = acc;
  }
}

extern "C" void kernel_launch(void* const* d_in, const int* in_sizes, int n_in,
                              void* d_out, int out_size, void* d_ws, size_t ws_size,
                              hipStream_t stream){
  const float* x      = (const float*)d_in[0];
  const float* conv_w = (const float*)d_in[1];
  const float* conv_b = (const float*)d_in[2];
  const float* stem_g = (const float*)d_in[3];
  const float* stem_b = (const float*)d_in[4];
  const float* pos_e  = (const float*)d_in[5];
  const float* coords = (const float*)d_in[6];
  const float* inW    = (const float*)d_in[7];
  const float* inb    = (const float*)d_in[8];
  const float* inWl   = (const float*)d_in[9];
  const float* inbl   = (const float*)d_in[10];
  const float* inWr   = (const float*)d_in[11];
  const float* inna   = (const float*)d_in[12];
  const float* ingw   = (const float*)d_in[13];
  const float* eg_eW  = (const float*)d_in[14];
  const float* eg_eb  = (const float*)d_in[15];
  const float* eg_sa  = (const float*)d_in[16];
  const float* eg_sb  = (const float*)d_in[17];
  const float* eg_nW  = (const float*)d_in[18];
  const float* eg_nb  = (const float*)d_in[19];
  const float* eg_Wl  = (const float*)d_in[20];
  const float* eg_bl  = (const float*)d_in[21];
  const float* eg_Wr  = (const float*)d_in[22];
  const float* eg_na  = (const float*)d_in[23];
  const float* eg_gw  = (const float*)d_in[24];
  const float* eg_aa  = (const float*)d_in[25];
  const float* eg_ab  = (const float*)d_in[26];
  const float* outW   = (const float*)d_in[27];
  const float* outb   = (const float*)d_in[28];
  const float* ong    = (const float*)d_in[29];
  const float* onb    = (const float*)d_in[30];
  const float* clsW   = (const float*)d_in[31];
  const float* clsb   = (const float*)d_in[32];
  const int*   cols   = (const int*)d_in[34];

  float* ws = (float*)d_ws;
  size_t off = 0;
  float* hbuf  = ws + off; off += (size_t)BNODES*256;   // h
  float* zbuf  = ws + off; off += (size_t)BNODES*256;   // z / x_mv / s
  float* abuf  = ws + off; off += (size_t)BNODES*256;   // nu
  float* g2    = ws + off; off += (size_t)NNODE*EMBC;
  float* pb2   = ws + off; off += (size_t)NNODE*EMBC;
  float* y0    = ws + off; off += (size_t)BNODES*EMBC;
  float* parts = ws + off; off += 896;
  float* stats = ws + off; off += 16;
  float* pp    = ws + off; off += 256*EMBC;
  float* pooled= ws + off; off += NBATCH*EMBC;

  k_tr   <<<NNODE, 192, 0, stream>>>(stem_g, stem_b, pos_e, g2, pb2);
  k_conv <<<NBATCH*FMAPC, 256, 0, stream>>>(x, conv_w, conv_b, y0, parts);
  k_stats<<<1, 64, 0, stream>>>(parts, stats);
  k_embed<<<BNODES/16, 256, 0, stream>>>(y0, stats, g2, pb2, inW, inb, coords, zbuf);
  k_sgp  <<<512, 512, 0, stream>>>(zbuf, hbuf, inWl, inbl, inWr, inna, ingw,
                                   (const float*)nullptr, (const float*)nullptr, 0, 49);
  for(int l = 0; l < NLAY; ++l){
    k_mvlin<<<512, 256, 0, stream>>>(hbuf, zbuf, eg_eW + (size_t)l*12288, 49);
    k_nu   <<<448, 512, 0, stream>>>(hbuf, zbuf, cols, eg_eb + l*64,
                                     eg_sa + l*192, eg_sb + l*192, abuf,
                                     eg_nW + (size_t)l*24576, eg_nb + l*64, 56);
    k_sgp  <<<512, 512, 0, stream>>>(abuf, hbuf, eg_Wl + (size_t)l*12288, eg_bl + l*64,
                                     eg_Wr + (size_t)l*12288, eg_na + l*192,
                                     eg_gw + l*640, eg_aa + l*192, eg_ab + l*192,
                                     (l==0)?1:2, 49);
  }
  k_head <<<1568, 192, 0, stream>>>(hbuf, outW, outb, ong, onb, zbuf, 16);
  k_pool1<<<256, 192, 0, stream>>>(zbuf, pp);
  k_pool2<<<8, 192, 0, stream>>>(pp, pooled);
  k_cls  <<<1, 128, 0, stream>>>(pooled, clsW, clsb, (float*)d_out);
}

// Round 4
// 1342.295 us; speedup vs baseline: 1.4370x; 1.4370x over previous
//
#include <hip/hip_runtime.h>
#include <hip/hip_bf16.h>
#include <math.h>

#define EMBC   192
#define NLAY   6
#define IMGC   224
#define FMAPC  56
#define NNODE  3136      // 56*56
#define NBATCH 8
#define BNODES 25088     // NBATCH*NNODE
#define KNNE   8
#define NT     64        // nodes per tile (= wavefront size)
#define RSQRT2 0.70710678118654752f

__device__ __forceinline__ float sigm(float x){ return 1.0f/(1.0f+__expf(-x)); }

// Stage a [NT][64ch][4bl] node-major global block into LDS with per-node column
// swizzle: element (n, m, bi) lives at xs[n*256 + ((m+n)&63)*4 + bi].
// Global reads coalesced; LDS writes 2-way (free); b128 reads bank-balanced.
__device__ __forceinline__ void stage_tile(float* xs, const float* __restrict__ g,
                                           int p0, int tid){
  for(int t = tid; t < NT*256; t += 256){
    int n = t >> 8, q = t & 255;
    int m = q >> 2, bi = q & 3;
    xs[(n<<8) + (((m + n) & 63)<<2) + bi] = g[((size_t)(p0+n)<<8) + q];
  }
}

// ---------------- K0: transpose stem_g / (stem_b+pos) to [n][c] ----------------
__global__ void k_tr(const float* __restrict__ g, const float* __restrict__ sb,
                     const float* __restrict__ pe, float* __restrict__ g2,
                     float* __restrict__ pb2){
  int n = blockIdx.x; int c = threadIdx.x;
  g2[n*EMBC + c]  = g[c*NNODE + n];
  pb2[n*EMBC + c] = sb[c*NNODE + n] + pe[c*NNODE + n];
}

// ---------------- K1: stem conv (4x4 stride 4) + LN partial sums ----------------
__global__ __launch_bounds__(256) void k_conv(const float* __restrict__ x,
    const float* __restrict__ cw, const float* __restrict__ cb,
    float* __restrict__ y0, float* __restrict__ parts){
  __shared__ float xs[2688];
  __shared__ float wsh[9216];
  __shared__ float red[512];
  int blk = blockIdx.x; int b = blk / FMAPC; int ph = blk % FMAPC;
  int tid = threadIdx.x;
  for(int t = tid; t < 9216; t += 256) wsh[t] = cw[t];
  for(int t = tid; t < 2688; t += 256){
    int r = t / IMGC; int w = t % IMGC;
    int ci = r >> 2, kh = r & 3;
    xs[t] = x[((size_t)(b*3 + ci)*IMGC + (ph*4 + kh))*IMGC + w];
  }
  __syncthreads();
  float s1 = 0.f, s2 = 0.f;
  for(int oi = tid; oi < FMAPC*EMBC; oi += 256){
    int pw = oi / EMBC; int c = oi % EMBC;
    float acc = cb[c];
    const float4* wv4 = (const float4*)(wsh + c*48);
    #pragma unroll
    for(int r = 0; r < 12; ++r){
      float4 xv = *((const float4*)(xs + r*IMGC + pw*4));
      float4 wv = wv4[r];
      acc += xv.x*wv.x + xv.y*wv.y + xv.z*wv.z + xv.w*wv.w;
    }
    y0[((size_t)(b*NNODE + ph*FMAPC + pw))*EMBC + c] = acc;
    s1 += acc; s2 += acc*acc;
  }
  red[tid] = s1; red[256+tid] = s2;
  __syncthreads();
  for(int st = 128; st > 0; st >>= 1){
    if(tid < st){ red[tid] += red[tid+st]; red[256+tid] += red[256+tid+st]; }
    __syncthreads();
  }
  if(tid == 0){ parts[blk*2] = red[0]; parts[blk*2+1] = red[256]; }
}

// ---------------- K2: finalize per-batch LN stats ----------------
__global__ void k_stats(const float* __restrict__ parts, float* __restrict__ stats){
  int b = threadIdx.x;
  if(b < NBATCH){
    float S = 0.f, Q = 0.f;
    for(int j = 0; j < FMAPC; ++j){ S += parts[(b*FMAPC+j)*2]; Q += parts[(b*FMAPC+j)*2+1]; }
    float cnt = (float)(EMBC*NNODE);
    float mu = S/cnt;
    float var = Q/cnt - mu*mu;
    stats[b*2] = mu; stats[b*2+1] = rsqrtf(var + 1e-5f);
  }
}

// ---------------- K3: LN + pos + embed + mvlin_flat(in_W) -> x_mv ----------------
// lane = node, wave-uniform ch -> in_W via scalar loads.
__global__ __launch_bounds__(256,2) void k_embed(const float* __restrict__ y0,
    const float* __restrict__ stats, const float* __restrict__ g2,
    const float* __restrict__ pb2, const float* __restrict__ inW,
    const float* __restrict__ inb, const float* __restrict__ coords,
    float* __restrict__ xmv){
  __shared__ float fs[NT*193];
  int tid = threadIdx.x, lane = tid & 63;
  int wid = __builtin_amdgcn_readfirstlane(tid >> 6);
  int ch0 = wid << 4;
  int p0 = blockIdx.x * NT;
  int b = p0 / NNODE; int n0 = p0 - b*NNODE;   // tile never spans batches (3136 = 49*64)
  float mu = stats[b*2], rstd = stats[b*2+1];
  for(int t = tid; t < NT*192; t += 256){
    int n = t / 192, c = t - n*192;
    int nn = n0 + n;
    fs[n*193 + c] = (y0[(size_t)(p0+n)*192 + c] - mu)*rstd*g2[nn*192+c] + pb2[nn*192+c];
  }
  __syncthreads();
  float acc[16];
  #pragma unroll
  for(int ci = 0; ci < 16; ++ci) acc[ci] = 0.f;
  for(int m = 0; m < 192; ++m){
    float xm = fs[lane*193 + m];
    #pragma unroll
    for(int ci = 0; ci < 16; ++ci)
      acc[ci] += inW[(size_t)(ch0+ci)*193 + m] * xm;
  }
  float cx = coords[(n0+lane)*2], cy = coords[(n0+lane)*2+1];
  #pragma unroll
  for(int ci = 0; ci < 16; ++ci){
    int ch = ch0 + ci;
    float wc = inW[(size_t)ch*193 + 192];
    float4 v; v.x = acc[ci] + inb[ch]; v.y = wc*cx; v.z = wc*cy; v.w = 0.f;
    *((float4*)(xmv + ((size_t)(p0+lane)*64 + ch)*4)) = v;
  }
}

// ---------------- K6: per-node edge gating + aggregation (z -> agg) ----------------
__global__ __launch_bounds__(256) void k_edge(const float* __restrict__ z,
    const int* __restrict__ cols, const float* __restrict__ eb,
    const float* __restrict__ sa, const float* __restrict__ sb,
    float* __restrict__ agg){
  int tid = threadIdx.x;
  int ch = tid & 63;
  int p = blockIdx.x*4 + (tid >> 6);
  float4 zo = *((const float4*)(z + ((size_t)p*64 + ch)*4));
  float bias = eb[ch];
  float a0 = sa[ch*3], a1 = sa[ch*3+1], a2 = sa[ch*3+2];
  float b0 = sb[ch*3], b1 = sb[ch*3+1], b2 = sb[ch*3+2];
  float ax=0.f, ay=0.f, az=0.f, aw=0.f;
  #pragma unroll
  for(int k = 0; k < KNNE; ++k){
    int c = cols[p*KNNE + k];
    float4 zc = *((const float4*)(z + ((size_t)c*64 + ch)*4));
    float d0 = zo.x - zc.x + bias;
    float d1 = zo.y - zc.y;
    float d2 = zo.z - zc.z;
    float d3 = zo.w - zc.w;
    float g0 = sigm(a0*d0 + b0);
    float g1 = sigm(a1*(d1*d1 + d2*d2) + b1);
    float g2v = sigm(a2*(d3*d3) + b2);
    ax += g0*d0; ay += g1*d1; az += g1*d2; aw += g2v*d3;
  }
  float4 acc; acc.x=ax; acc.y=ay; acc.z=az; acc.w=aw;
  *((float4*)(agg + ((size_t)p*64 + ch)*4)) = acc;
}

// ---------------- K7: nu = nW * concat[h, agg] + nb  (two staged K=64 passes) ----------------
__global__ __launch_bounds__(256,2) void k_nu(const float* __restrict__ h,
    const float* __restrict__ agg, float* __restrict__ nu,
    const float* __restrict__ W, const float* __restrict__ nb){
  __shared__ float xs[NT*256];
  int tid = threadIdx.x, lane = tid & 63;
  int wid = __builtin_amdgcn_readfirstlane(tid >> 6);
  int ch0 = wid << 4;
  int p0 = blockIdx.x * NT;
  float acc[16][4];
  #pragma unroll
  for(int ci = 0; ci < 16; ++ci)
    #pragma unroll
    for(int bi = 0; bi < 4; ++bi) acc[ci][bi] = 0.f;
  const float* xbase = xs + (lane<<8);

  stage_tile(xs, h, p0, tid);
  __syncthreads();
  #pragma unroll 1
  for(int m = 0; m < 64; ++m){
    float4 xv = *((const float4*)(xbase + (((m + lane)&63)<<2)));
    #pragma unroll
    for(int ci = 0; ci < 16; ++ci){
      const float* wp = W + ((size_t)(ch0+ci)*128 + m)*3;
      float w0 = wp[0], w1 = wp[1], w2 = wp[2];
      acc[ci][0] += w0*xv.x; acc[ci][1] += w1*xv.y;
      acc[ci][2] += w1*xv.z; acc[ci][3] += w2*xv.w;
    }
  }
  __syncthreads();   // all waves done reading before restage
  stage_tile(xs, agg, p0, tid);
  __syncthreads();
  #pragma unroll 1
  for(int m = 0; m < 64; ++m){
    float4 xv = *((const float4*)(xbase + (((m + lane)&63)<<2)));
    #pragma unroll
    for(int ci = 0; ci < 16; ++ci){
      const float* wp = W + ((size_t)(ch0+ci)*128 + 64 + m)*3;
      float w0 = wp[0], w1 = wp[1], w2 = wp[2];
      acc[ci][0] += w0*xv.x; acc[ci][1] += w1*xv.y;
      acc[ci][2] += w1*xv.z; acc[ci][3] += w2*xv.w;
    }
  }
  int p = p0 + lane;
  #pragma unroll
  for(int ci = 0; ci < 16; ++ci){
    int ch = ch0 + ci;
    float4 v; v.x = acc[ci][0] + nb[ch]; v.y = acc[ci][1];
    v.z = acc[ci][2]; v.w = acc[ci][3];
    *((float4*)(nu + ((size_t)p*64 + ch)*4)) = v;
  }
}

// ---------------- K8: sgp (+silu +residual) + fused z = eW * h_new ----------------
// mode 0: h = sgp(src); mode 1: h = silu(sgp(src)); mode 2: h += silu(sgp(src))
// if zW != null: additionally zout = mvlin(h_new, zW)  (no bias)
__global__ __launch_bounds__(256,2) void k_sgp(const float* __restrict__ src,
    float* __restrict__ h, const float* __restrict__ Wl, const float* __restrict__ bl,
    const float* __restrict__ Wr, const float* __restrict__ na,
    const float* __restrict__ gw, const float* __restrict__ aa,
    const float* __restrict__ ab, int mode,
    const float* __restrict__ zW, float* __restrict__ zout){
  __shared__ float xs[NT*256];   // 64 KB
  int tid = threadIdx.x, lane = tid & 63;
  int wid = __builtin_amdgcn_readfirstlane(tid >> 6);
  int ch0 = wid << 4;
  int p0 = blockIdx.x * NT;
  stage_tile(xs, src, p0, tid);
  __syncthreads();
  float accl[16][4], accr[16][4];
  #pragma unroll
  for(int ci = 0; ci < 16; ++ci)
    #pragma unroll
    for(int bi = 0; bi < 4; ++bi){ accl[ci][bi] = 0.f; accr[ci][bi] = 0.f; }
  const float* xbase = xs + (lane<<8);
  #pragma unroll 1
  for(int m = 0; m < 64; ++m){
    float4 xv = *((const float4*)(xbase + (((m + lane)&63)<<2)));
    #pragma unroll
    for(int ci = 0; ci < 16; ++ci){
      const float* wlp = Wl + ((size_t)(ch0+ci)*64 + m)*3;
      const float* wrp = Wr + ((size_t)(ch0+ci)*64 + m)*3;
      float wl0 = wlp[0], wl1 = wlp[1], wl2 = wlp[2];
      float wr0 = wrp[0], wr1 = wrp[1], wr2 = wrp[2];
      accl[ci][0] += wl0*xv.x; accl[ci][1] += wl1*xv.y;
      accl[ci][2] += wl1*xv.z; accl[ci][3] += wl2*xv.w;
      accr[ci][0] += wr0*xv.x; accr[ci][1] += wr1*xv.y;
      accr[ci][2] += wr1*xv.z; accr[ci][3] += wr2*xv.w;
    }
  }
  float vout[16][4];
  int p = p0 + lane;
  #pragma unroll
  for(int ci = 0; ci < 16; ++ci){
    int ch = ch0 + ci;
    // normalize_mv on the Wr branch (all blades lane-local)
    float yr0 = accr[ci][0], yr1 = accr[ci][1], yr2 = accr[ci][2], yr3 = accr[ci][3];
    float na0 = sigm(na[ch*3]), na1 = sigm(na[ch*3+1]), na2 = sigm(na[ch*3+2]);
    float d0 = na0*(sqrtf(yr0*yr0 + 1e-12f) - 1.f) + 1.f + 1e-6f;
    float d1 = na1*(sqrtf(yr1*yr1 + yr2*yr2 + 1e-12f) - 1.f) + 1.f + 1e-6f;
    float d2 = na2*(sqrtf(yr3*yr3 + 1e-12f) - 1.f) + 1.f + 1e-6f;
    float xr0 = yr0/d0, xr1 = yr1/d1, xr2 = yr2/d1, xr3 = yr3/d2;
    // geometric product with per-path weights (x from LDS, m-index = ch)
    float4 xv = *((const float4*)(xbase + (((ch + lane)&63)<<2)));
    const float* gwp = gw + ch*10;
    float gp0 = gwp[0]*xv.x*xr0 + gwp[3]*(xv.y*xr1 + xv.z*xr2) + gwp[7]*xv.w*xr3;
    float gp1 = gwp[1]*xv.x*xr1 + gwp[4]*xv.y*xr0 - gwp[5]*xv.z*xr3 - gwp[8]*xv.w*xr2;
    float gp2 = gwp[1]*xv.x*xr2 + gwp[4]*xv.z*xr0 + gwp[5]*xv.y*xr3 + gwp[8]*xv.w*xr1;
    float gp3 = gwp[2]*xv.x*xr3 + gwp[6]*(xv.y*xr2 - xv.z*xr1) - gwp[9]*xv.w*xr0;
    float o0 = (accl[ci][0] + bl[ch] + gp0)*RSQRT2;
    float o1 = (accl[ci][1] + gp1)*RSQRT2;
    float o2 = (accl[ci][2] + gp2)*RSQRT2;
    float o3 = (accl[ci][3] + gp3)*RSQRT2;
    float v0, v1, v2, v3;
    if(mode == 0){ v0 = o0; v1 = o1; v2 = o2; v3 = o3; }
    else{
      float g0 = sigm(aa[ch*3]*o0 + ab[ch*3]);
      float g1 = sigm(aa[ch*3+1]*(o1*o1 + o2*o2) + ab[ch*3+1]);
      float g2v = sigm(aa[ch*3+2]*(o3*o3) + ab[ch*3+2]);
      v0 = g0*o0; v1 = g1*o1; v2 = g1*o2; v3 = g2v*o3;
      if(mode == 2){
        float4 hp = *((const float4*)(h + ((size_t)p*64 + ch)*4));
        v0 += hp.x; v1 += hp.y; v2 += hp.z; v3 += hp.w;
      }
    }
    float4 vv; vv.x=v0; vv.y=v1; vv.z=v2; vv.w=v3;
    *((float4*)(h + ((size_t)p*64 + ch)*4)) = vv;
    vout[ci][0]=v0; vout[ci][1]=v1; vout[ci][2]=v2; vout[ci][3]=v3;
  }
  if(zW != nullptr){
    __syncthreads();   // everyone done reading xs
    #pragma unroll
    for(int ci = 0; ci < 16; ++ci){
      int ch = ch0 + ci;
      float4 vv; vv.x=vout[ci][0]; vv.y=vout[ci][1]; vv.z=vout[ci][2]; vv.w=vout[ci][3];
      *((float4*)(xs + (lane<<8) + (((ch + lane)&63)<<2))) = vv;
    }
    __syncthreads();
    float accz[16][4];
    #pragma unroll
    for(int ci = 0; ci < 16; ++ci)
      #pragma unroll
      for(int bi = 0; bi < 4; ++bi) accz[ci][bi] = 0.f;
    #pragma unroll 1
    for(int m = 0; m < 64; ++m){
      float4 xv = *((const float4*)(xbase + (((m + lane)&63)<<2)));
      #pragma unroll
      for(int ci = 0; ci < 16; ++ci){
        const float* wp = zW + ((size_t)(ch0+ci)*64 + m)*3;
        float w0 = wp[0], w1 = wp[1], w2 = wp[2];
        accz[ci][0] += w0*xv.x; accz[ci][1] += w1*xv.y;
        accz[ci][2] += w1*xv.z; accz[ci][3] += w2*xv.w;
      }
    }
    #pragma unroll
    for(int ci = 0; ci < 16; ++ci){
      int ch = ch0 + ci;
      float4 v; v.x=accz[ci][0]; v.y=accz[ci][1]; v.z=accz[ci][2]; v.w=accz[ci][3];
      *((float4*)(zout + ((size_t)p*64 + ch)*4)) = v;
    }
  }
}

// ---------------- K9: head projection (blade 0) + per-node LN ----------------
__global__ __launch_bounds__(256,2) void k_head(const float* __restrict__ h,
    const float* __restrict__ oW, const float* __restrict__ ob,
    const float* __restrict__ ong, const float* __restrict__ onb,
    float* __restrict__ s){
  __shared__ float hs[NT*65];
  __shared__ float rr[512];
  int tid = threadIdx.x, lane = tid & 63;
  int wid = __builtin_amdgcn_readfirstlane(tid >> 6);
  int c0 = wid*48;
  int p0 = blockIdx.x * NT;
  for(int t = tid; t < NT*64; t += 256){
    int n = t >> 6, c = t & 63;
    hs[n*65 + c] = h[(((size_t)(p0+n))*64 + c)*4];
  }
  __syncthreads();
  float a[48];
  #pragma unroll
  for(int ci = 0; ci < 48; ++ci) a[ci] = 0.f;
  #pragma unroll 1
  for(int m = 0; m < 64; ++m){
    float xm = hs[lane*65 + m];
    #pragma unroll
    for(int ci = 0; ci < 48; ++ci)
      a[ci] += oW[(size_t)(c0+ci)*64 + m] * xm;
  }
  float s1 = 0.f, s2 = 0.f;
  #pragma unroll
  for(int ci = 0; ci < 48; ++ci){
    a[ci] += ob[c0+ci];
    s1 += a[ci]; s2 += a[ci]*a[ci];
  }
  rr[wid*64 + lane] = s1; rr[256 + wid*64 + lane] = s2;
  __syncthreads();
  float S = rr[lane] + rr[64+lane] + rr[128+lane] + rr[192+lane];
  float Q = rr[256+lane] + rr[320+lane] + rr[384+lane] + rr[448+lane];
  float mu = S*(1.0f/EMBC);
  float var = Q*(1.0f/EMBC) - mu*mu;
  float rstd = rsqrtf(var + 1e-5f);
  #pragma unroll
  for(int q = 0; q < 12; ++q){
    int c = c0 + q*4;
    float4 v;
    v.x = (a[q*4  ] - mu)*rstd*ong[c  ] + onb[c  ];
    v.y = (a[q*4+1] - mu)*rstd*ong[c+1] + onb[c+1];
    v.z = (a[q*4+2] - mu)*rstd*ong[c+2] + onb[c+2];
    v.w = (a[q*4+3] - mu)*rstd*ong[c+3] + onb[c+3];
    *((float4*)(s + (size_t)(p0+lane)*192 + c)) = v;
  }
}

// ---------------- K10: pooling (two-stage, deterministic) ----------------
__global__ void k_pool1(const float* __restrict__ s, float* __restrict__ pp){
  int blk = blockIdx.x;
  int b = blk >> 5, chunk = blk & 31;
  int c = threadIdx.x;
  float acc = 0.f;
  int n0 = chunk*98;
  for(int j = 0; j < 98; ++j) acc += s[((size_t)(b*NNODE + n0 + j))*EMBC + c];
  pp[(size_t)blk*EMBC + c] = acc;
}
__global__ void k_pool2(const float* __restrict__ pp, float* __restrict__ pooled){
  int b = blockIdx.x; int c = threadIdx.x;
  float acc = 0.f;
  for(int j = 0; j < 32; ++j) acc += pp[((size_t)(b*32 + j))*EMBC + c];
  pooled[b*EMBC + c] = acc * (1.0f/NNODE);
}

// ---------------- K11: classifier ----------------
__global__ void k_cls(const float* __restrict__ pooled, const float* __restrict__ cW,
                      const float* __restrict__ cb, float* __restrict__ out){
  int tid = threadIdx.x;
  if(tid < NBATCH*10){
    int b = tid/10, k = tid%10;
    float acc = cb[k];
    for(int c = 0; c < EMBC; ++c) acc += pooled[b*EMBC + c]*cW[k*EMBC + c];
    out[tid] = acc;
  }
}

extern "C" void kernel_launch(void* const* d_in, const int* in_sizes, int n_in,
                              void* d_out, int out_size, void* d_ws, size_t ws_size,
                              hipStream_t stream){
  const float* x      = (const float*)d_in[0];
  const float* conv_w = (const float*)d_in[1];
  const float* conv_b = (const float*)d_in[2];
  const float* stem_g = (const float*)d_in[3];
  const float* stem_b = (const float*)d_in[4];
  const float* pos_e  = (const float*)d_in[5];
  const float* coords = (const float*)d_in[6];
  const float* inW    = (const float*)d_in[7];
  const float* inb    = (const float*)d_in[8];
  const float* inWl   = (const float*)d_in[9];
  const float* inbl   = (const float*)d_in[10];
  const float* inWr   = (const float*)d_in[11];
  const float* inna   = (const float*)d_in[12];
  const float* ingw   = (const float*)d_in[13];
  const float* eg_eW  = (const float*)d_in[14];
  const float* eg_eb  = (const float*)d_in[15];
  const float* eg_sa  = (const float*)d_in[16];
  const float* eg_sb  = (const float*)d_in[17];
  const float* eg_nW  = (const float*)d_in[18];
  const float* eg_nb  = (const float*)d_in[19];
  const float* eg_Wl  = (const float*)d_in[20];
  const float* eg_bl  = (const float*)d_in[21];
  const float* eg_Wr  = (const float*)d_in[22];
  const float* eg_na  = (const float*)d_in[23];
  const float* eg_gw  = (const float*)d_in[24];
  const float* eg_aa  = (const float*)d_in[25];
  const float* eg_ab  = (const float*)d_in[26];
  const float* outW   = (const float*)d_in[27];
  const float* outb   = (const float*)d_in[28];
  const float* ong    = (const float*)d_in[29];
  const float* onb    = (const float*)d_in[30];
  const float* clsW   = (const float*)d_in[31];
  const float* clsb   = (const float*)d_in[32];
  const int*   cols   = (const int*)d_in[34];   // rows[p*8+k] == p by construction

  float* ws = (float*)d_ws;
  size_t off = 0;
  float* hbuf  = ws + off; off += (size_t)BNODES*256;   // h
  float* bigA  = ws + off; off += (size_t)BNODES*256;   // x_mv / agg / nu (ping-pong)
  float* bigB  = ws + off; off += (size_t)BNODES*256;   // z / nu (ping-pong)
  float* g2    = ws + off; off += (size_t)NNODE*EMBC;
  float* pb2   = ws + off; off += (size_t)NNODE*EMBC;
  float* y0    = ws + off; off += (size_t)BNODES*EMBC;
  float* parts = ws + off; off += 896;
  float* stats = ws + off; off += 16;
  float* pp    = ws + off; off += 256*EMBC;
  float* pooled= ws + off; off += NBATCH*EMBC;

  const int NTILE = BNODES/NT;   // 392

  k_tr   <<<NNODE, 192, 0, stream>>>(stem_g, stem_b, pos_e, g2, pb2);
  k_conv <<<NBATCH*FMAPC, 256, 0, stream>>>(x, conv_w, conv_b, y0, parts);
  k_stats<<<1, 64, 0, stream>>>(parts, stats);
  k_embed<<<NTILE, 256, 0, stream>>>(y0, stats, g2, pb2, inW, inb, coords, bigA);
  // input sgp: h = sgp(x_mv); fused z0 = eW[0] * h
  k_sgp  <<<NTILE, 256, 0, stream>>>(bigA, hbuf, inWl, inbl, inWr, inna, ingw,
                                     (const float*)nullptr, (const float*)nullptr, 0,
                                     eg_eW, bigB);
  float* zcur = bigB;   // z lives here entering each layer
  float* spare = bigA;
  for(int l = 0; l < NLAY; ++l){
    // agg <- spare ; nu <- zcur (z dead after k_edge) ; z_next <- spare (agg dead after k_nu)
    k_edge <<<BNODES/4, 256, 0, stream>>>(zcur, cols, eg_eb + l*64,
                                          eg_sa + l*192, eg_sb + l*192, spare);
    k_nu   <<<NTILE, 256, 0, stream>>>(hbuf, spare, zcur,
                                       eg_nW + (size_t)l*24576, eg_nb + l*64);
    const float* zWn = (l < NLAY-1) ? (eg_eW + (size_t)(l+1)*12288) : (const float*)nullptr;
    k_sgp  <<<NTILE, 256, 0, stream>>>(zcur, hbuf, eg_Wl + (size_t)l*12288, eg_bl + l*64,
                                       eg_Wr + (size_t)l*12288, eg_na + l*192,
                                       eg_gw + l*640, eg_aa + l*192, eg_ab + l*192,
                                       (l==0)?1:2, zWn, spare);
    // swap: z_next now in `spare`
    float* t = zcur; zcur = spare; spare = t;
  }
  k_head <<<NTILE, 256, 0, stream>>>(hbuf, outW, outb, ong, onb, spare);
  k_pool1<<<256, 192, 0, stream>>>(spare, pp);
  k_pool2<<<8, 192, 0, stream>>>(pp, pooled);
  k_cls  <<<1, 128, 0, stream>>>(pooled, clsW, clsb, (float*)d_out);
}